// Round 1
// baseline (245.810 us; speedup 1.0000x reference)
//
#include <hip/hip_runtime.h>

// SAHead: B=2, Cenc=326, C=320, dk=dv=64, L=64*64=4096.
// Cosine attention => scores in [-1,1] => exp() stable without max-subtraction
// => split-j partial softmax combines by plain addition.

#define L_DIM 4096
#define NSPLIT 4

typedef __attribute__((ext_vector_type(8))) short bf16x8;  // 8 bf16 (4 VGPRs)
typedef __attribute__((ext_vector_type(4))) float f32x4;   // 4 fp32 acc

__device__ __forceinline__ unsigned short f2bf(float f) {
    // round-to-nearest-even fp32 -> bf16
    unsigned u = __float_as_uint(f);
    u += 0x7fffu + ((u >> 16) & 1u);
    return (unsigned short)(u >> 16);
}

// ---------------------------------------------------------------------------
// Kernel 1: 1x1-conv projections.
// grid (4, 64, 6): x = l-chunk (1024 l / 4 per thread), y = out channel d,
// z = tensor*2 + batch  (tensor 0=Q, 1=K, 2=V).
// Q,K raw fp32 [b][d][L] (coalesced float4 stores); V bf16 [b][v][L].
// ---------------------------------------------------------------------------
__global__ __launch_bounds__(256) void proj_kernel(
    const float* __restrict__ x, const float* __restrict__ xe,
    const float* __restrict__ Wq, const float* __restrict__ bq,
    const float* __restrict__ Wk, const float* __restrict__ bk,
    const float* __restrict__ Wv, const float* __restrict__ bv,
    float* __restrict__ qraw, float* __restrict__ kraw,
    unsigned short* __restrict__ vbf)
{
    const int z = blockIdx.z;
    const int tensor = z >> 1, b = z & 1;
    const int d = blockIdx.y;
    const int l0 = (blockIdx.x * 256 + threadIdx.x) * 4;

    const float* W; const float* bias; const float* in; int Cin;
    if (tensor == 0)      { W = Wq; bias = bq; in = xe; Cin = 326; }
    else if (tensor == 1) { W = Wk; bias = bk; in = xe; Cin = 326; }
    else                  { W = Wv; bias = bv; in = x;  Cin = 320; }

    const float* src  = in + (size_t)b * Cin * L_DIM + l0;
    const float* wrow = W + (size_t)d * Cin;   // wave-uniform -> s_load

    float a0 = 0.f, a1 = 0.f, a2 = 0.f, a3 = 0.f;
    for (int c = 0; c < Cin; ++c) {
        const float w = wrow[c];
        const float4 xv = *(const float4*)(src + (size_t)c * L_DIM);
        a0 += w * xv.x; a1 += w * xv.y; a2 += w * xv.z; a3 += w * xv.w;
    }
    const float bb = bias[d];
    a0 += bb; a1 += bb; a2 += bb; a3 += bb;

    if (tensor < 2) {
        float* dst = (tensor ? kraw : qraw) + (size_t)(b * 64 + d) * L_DIM + l0;
        float4 o; o.x = a0; o.y = a1; o.z = a2; o.w = a3;
        *(float4*)dst = o;
    } else {
        ushort4 o; o.x = f2bf(a0); o.y = f2bf(a1); o.z = f2bf(a2); o.w = f2bf(a3);
        *(ushort4*)(vbf + (size_t)(b * 64 + d) * L_DIM + l0) = o;
    }
}

// ---------------------------------------------------------------------------
// Kernel 2: L2-normalize over channels; transpose to [b][l][64] bf16
// (the MFMA A/B operand layout for QK^T: 8 contiguous d per lane).
// grid (64, 2, 2): x = l-tile, y = b, z = 0:Q / 1:K.
// ---------------------------------------------------------------------------
__global__ __launch_bounds__(256) void norm_kernel(
    const float* __restrict__ qraw, const float* __restrict__ kraw,
    unsigned short* __restrict__ qn, unsigned short* __restrict__ kn)
{
    const int which = blockIdx.z, b = blockIdx.y;
    const int l0 = blockIdx.x * 64;
    const float* raw = which ? kraw : qraw;
    unsigned short* outp = which ? kn : qn;

    __shared__ float tile[64][65];   // [d][l], +1 pad
    __shared__ float rn[64];
    const int tid = threadIdx.x;

    for (int idx = tid; idx < 4096; idx += 256) {
        const int d = idx >> 6, l = idx & 63;
        tile[d][l] = raw[(size_t)(b * 64 + d) * L_DIM + l0 + l];
    }
    __syncthreads();
    if (tid < 64) {
        float s = 0.f;
        for (int d = 0; d < 64; ++d) { const float v = tile[d][tid]; s += v * v; }
        rn[tid] = 1.0f / fmaxf(sqrtf(s), 1e-6f);   // x / max(||x||, eps)
    }
    __syncthreads();
    for (int idx = tid; idx < 4096; idx += 256) {
        const int l = idx >> 6, d = idx & 63;      // d fastest -> coalesced store
        outp[((size_t)b * L_DIM + l0 + l) * 64 + d] = f2bf(tile[d][l] * rn[l]);
    }
}

// ---------------------------------------------------------------------------
// Kernel 3: attention with split-j partial softmax (no max rescale needed).
// grid (64, NSPLIT, 2): x = 64-row i-tile, y = j-split, z = b. 4 waves/block,
// wave w owns i-strip [16w,16w+16). No __syncthreads in the j-loop: the P
// transform LDS strip is wave-private.
// MFMA 16x16x32 bf16 layouts (verified, m89/m120):
//   A: lane holds A[m=lane&15][k=(lane>>4)*8+j]   (8 contiguous k)
//   B: lane holds B[k=(lane>>4)*8+j][n=lane&15]
//   C/D: lane holds D[row=(lane>>4)*4+reg][col=lane&15]
// ---------------------------------------------------------------------------
__global__ __launch_bounds__(256) void attn_kernel(
    const unsigned short* __restrict__ qn, const unsigned short* __restrict__ kn,
    const unsigned short* __restrict__ vbf,
    float* __restrict__ opart, float* __restrict__ ssum)
{
    const int b = blockIdx.z, split = blockIdx.y;
    const int i0 = blockIdx.x * 64;
    const int tid = threadIdx.x;
    const int w = tid >> 6, lane = tid & 63, q = lane >> 4, ln = lane & 15;

    const unsigned short* Q = qn + (size_t)b * L_DIM * 64;   // [l][64]
    const unsigned short* K = kn + (size_t)b * L_DIM * 64;   // [l][64]
    const unsigned short* V = vbf + (size_t)b * 64 * L_DIM;  // [v][L]

    __shared__ unsigned short Pl[64][72];   // [i][j] bf16, wave-private 16-row strips

    // Q A-fragments: rows i = i0+16w+ln, k-steps d in [0,32),[32,64). Live all loop.
    bf16x8 qa[2];
    {
        const unsigned short* qp = Q + (size_t)(i0 + w * 16 + ln) * 64 + q * 8;
        qa[0] = *(const bf16x8*)(qp);
        qa[1] = *(const bf16x8*)(qp + 32);
    }

    f32x4 acc[4];   // O strip [16 i][64 v]: 4 C-frags over v
    #pragma unroll
    for (int vf = 0; vf < 4; ++vf) acc[vf] = (f32x4){0.f, 0.f, 0.f, 0.f};
    float rowsum[4] = {0.f, 0.f, 0.f, 0.f};
    const f32x4 zero = (f32x4){0.f, 0.f, 0.f, 0.f};

    const int JT = L_DIM / (NSPLIT * 64);   // 16 j-tiles per split
    for (int jt = 0; jt < JT; ++jt) {
        const int j0 = split * (L_DIM / NSPLIT) + jt * 64;

        // K B-fragments: B[k=d][n=j] = Kn[j][d]
        bf16x8 kf[4][2];
        #pragma unroll
        for (int jf = 0; jf < 4; ++jf) {
            const unsigned short* kp = K + (size_t)(j0 + jf * 16 + ln) * 64 + q * 8;
            kf[jf][0] = *(const bf16x8*)(kp);
            kf[jf][1] = *(const bf16x8*)(kp + 32);
        }

        // S strip = Qn . Kn^T  (16 i x 64 j)
        f32x4 s[4];
        #pragma unroll
        for (int jf = 0; jf < 4; ++jf) {
            s[jf] = __builtin_amdgcn_mfma_f32_16x16x32_bf16(qa[0], kf[jf][0], zero, 0, 0, 0);
            s[jf] = __builtin_amdgcn_mfma_f32_16x16x32_bf16(qa[1], kf[jf][1], s[jf], 0, 0, 0);
        }

        // P = exp(S) (S in [-1,1]: stable); rowsum; pack bf16 into LDS strip
        #pragma unroll
        for (int jf = 0; jf < 4; ++jf) {
            #pragma unroll
            for (int r = 0; r < 4; ++r) {
                const float p = __expf(s[jf][r]);
                rowsum[r] += p;
                Pl[w * 16 + q * 4 + r][jf * 16 + ln] = f2bf(p);
            }
        }

        // P back out in A-operand layout (8 contiguous j per lane)
        bf16x8 pa[2];
        {
            const unsigned short* pp = &Pl[w * 16 + ln][q * 8];
            pa[0] = *(const bf16x8*)(pp);
            pa[1] = *(const bf16x8*)(pp + 32);
        }

        // O += P . V   (V[v][L]: lane reads 8 contiguous j at fixed v = B layout)
        #pragma unroll
        for (int vf = 0; vf < 4; ++vf) {
            const unsigned short* vp = V + (size_t)(vf * 16 + ln) * L_DIM + j0 + q * 8;
            const bf16x8 v0 = *(const bf16x8*)(vp);
            const bf16x8 v1 = *(const bf16x8*)(vp + 32);
            acc[vf] = __builtin_amdgcn_mfma_f32_16x16x32_bf16(pa[0], v0, acc[vf], 0, 0, 0);
            acc[vf] = __builtin_amdgcn_mfma_f32_16x16x32_bf16(pa[1], v1, acc[vf], 0, 0, 0);
        }
    }

    // full row sums: reduce across the 16 lanes (cols) of each quad
    #pragma unroll
    for (int off = 1; off < 16; off <<= 1)
        #pragma unroll
        for (int r = 0; r < 4; ++r) rowsum[r] += __shfl_xor(rowsum[r], off);

    float* Op = opart + ((size_t)(b * NSPLIT + split) * L_DIM + i0) * 64;
    #pragma unroll
    for (int vf = 0; vf < 4; ++vf)
        #pragma unroll
        for (int r = 0; r < 4; ++r)
            Op[(w * 16 + q * 4 + r) * 64 + vf * 16 + ln] = acc[vf][r];

    if (ln == 0) {
        #pragma unroll
        for (int r = 0; r < 4; ++r)
            ssum[(size_t)(b * NSPLIT + split) * L_DIM + i0 + w * 16 + q * 4 + r] = rowsum[r];
    }
}

// ---------------------------------------------------------------------------
// Kernel 4: sum the NSPLIT partials, divide by rowsum, transpose to out [b][v][l].
// grid (64, 2): x = i-tile, y = b.
// ---------------------------------------------------------------------------
__global__ __launch_bounds__(256) void combine_kernel(
    const float* __restrict__ opart, const float* __restrict__ ssum,
    float* __restrict__ out)
{
    const int b = blockIdx.y;
    const int i0 = blockIdx.x * 64;
    const int tid = threadIdx.x;
    __shared__ float t[64][65];
    __shared__ float sinv[64];

    if (tid < 64) {
        float s = 0.f;
        for (int sp = 0; sp < NSPLIT; ++sp)
            s += ssum[(size_t)(b * NSPLIT + sp) * L_DIM + i0 + tid];
        sinv[tid] = 1.0f / s;
    }
    __syncthreads();
    for (int idx = tid; idx < 4096; idx += 256) {
        const int i = idx >> 6, v = idx & 63;   // v fastest -> coalesced reads
        float a = 0.f;
        for (int sp = 0; sp < NSPLIT; ++sp)
            a += opart[((size_t)(b * NSPLIT + sp) * L_DIM + i0 + i) * 64 + v];
        t[i][v] = a;
    }
    __syncthreads();
    for (int idx = tid; idx < 4096; idx += 256) {
        const int v = idx >> 6, i = idx & 63;   // i fastest -> coalesced stores
        out[((size_t)(b * 64 + v)) * L_DIM + i0 + i] = t[i][v] * sinv[i];
    }
}

// ---------------------------------------------------------------------------
extern "C" void kernel_launch(void* const* d_in, const int* in_sizes, int n_in,
                              void* d_out, int out_size, void* d_ws, size_t ws_size,
                              hipStream_t stream)
{
    const float* x  = (const float*)d_in[0];
    const float* xe = (const float*)d_in[1];
    const float* Wq = (const float*)d_in[2];
    const float* bq = (const float*)d_in[3];
    const float* Wk = (const float*)d_in[4];
    const float* bk = (const float*)d_in[5];
    const float* Wv = (const float*)d_in[6];
    const float* bv = (const float*)d_in[7];
    float* out = (float*)d_out;

    char* ws = (char*)d_ws;
    float*          qraw = (float*)(ws);                          // 2 MB
    float*          kraw = (float*)(ws + (2u << 20));             // 2 MB
    unsigned short* qn   = (unsigned short*)(ws + (4u << 20));    // 1 MB
    unsigned short* kn   = (unsigned short*)(ws + (5u << 20));    // 1 MB
    unsigned short* vbf  = (unsigned short*)(ws + (6u << 20));    // 1 MB
    float*          op   = (float*)(ws + (7u << 20));             // 8 MB
    float*          ss   = (float*)(ws + (15u << 20));            // 128 KB

    proj_kernel<<<dim3(4, 64, 6), 256, 0, stream>>>(x, xe, Wq, bq, Wk, bk, Wv, bv,
                                                    qraw, kraw, vbf);
    norm_kernel<<<dim3(64, 2, 2), 256, 0, stream>>>(qraw, kraw, qn, kn);
    attn_kernel<<<dim3(64, NSPLIT, 2), 256, 0, stream>>>(qn, kn, vbf, op, ss);
    combine_kernel<<<dim3(64, 2), 256, 0, stream>>>(op, ss, out);
}

// Round 2
// 212.932 us; speedup vs baseline: 1.1544x; 1.1544x over previous
//
#include <hip/hip_runtime.h>

// SAHead: B=2, Cenc=326, C=320, dk=dv=64, L=64*64=4096.
// Cosine attention => scores in [-1,1] => exp() stable without max-subtraction
// => split-j partial softmax combines by plain addition.

#define L_DIM 4096
#define NSPLIT 4

typedef __attribute__((ext_vector_type(8))) short bf16x8;  // 8 bf16 (4 VGPRs)
typedef __attribute__((ext_vector_type(4))) float f32x4;   // 4 fp32 acc

__device__ __forceinline__ unsigned short f2bf(float f) {
    // round-to-nearest-even fp32 -> bf16
    unsigned u = __float_as_uint(f);
    u += 0x7fffu + ((u >> 16) & 1u);
    return (unsigned short)(u >> 16);
}

// ---------------------------------------------------------------------------
// Kernel 1: 1x1-conv projections as register-blocked GEMM.
// grid (8, 8, 6): x = 512-l chunk (128 thr x 4 l), y = 8-d group,
// z = tensor*2 + batch (tensor 0=Q, 1=K, 2=V).
// Each block: 8 d x 512 l. 32 fp32 accumulators/thread; weights via wave-
// uniform s_loads; unroll 2 keeps multiple float4 loads in flight.
// 8x less L2 traffic than one-d-per-block (each x elem read 8x, not 64x).
// ---------------------------------------------------------------------------
__global__ __launch_bounds__(128) void proj_kernel(
    const float* __restrict__ x, const float* __restrict__ xe,
    const float* __restrict__ Wq, const float* __restrict__ bq,
    const float* __restrict__ Wk, const float* __restrict__ bk,
    const float* __restrict__ Wv, const float* __restrict__ bv,
    float* __restrict__ qraw, float* __restrict__ kraw,
    unsigned short* __restrict__ vbf)
{
    const int z = blockIdx.z;
    const int tensor = z >> 1, b = z & 1;
    const int d0 = blockIdx.y * 8;
    const int l0 = blockIdx.x * 512 + threadIdx.x * 4;

    const float* W; const float* bias; const float* in; int Cin;
    if (tensor == 0)      { W = Wq; bias = bq; in = xe; Cin = 326; }
    else if (tensor == 1) { W = Wk; bias = bk; in = xe; Cin = 326; }
    else                  { W = Wv; bias = bv; in = x;  Cin = 320; }

    const float* src = in + (size_t)b * Cin * L_DIM + l0;
    const float* w0  = W + (size_t)d0 * Cin;   // wave-uniform rows -> s_loads

    float acc[8][4];
    #pragma unroll
    for (int i = 0; i < 8; ++i)
        #pragma unroll
        for (int r = 0; r < 4; ++r) acc[i][r] = 0.f;

    #pragma unroll 2
    for (int c = 0; c < Cin; ++c) {
        const float4 xv = *(const float4*)(src + (size_t)c * L_DIM);
        #pragma unroll
        for (int i = 0; i < 8; ++i) {
            const float w = w0[(size_t)i * Cin + c];
            acc[i][0] += w * xv.x; acc[i][1] += w * xv.y;
            acc[i][2] += w * xv.z; acc[i][3] += w * xv.w;
        }
    }

    #pragma unroll
    for (int i = 0; i < 8; ++i) {
        const float bb = bias[d0 + i];
        const float a0 = acc[i][0] + bb, a1 = acc[i][1] + bb;
        const float a2 = acc[i][2] + bb, a3 = acc[i][3] + bb;
        if (tensor < 2) {
            float* dst = (tensor ? kraw : qraw)
                       + (size_t)(b * 64 + d0 + i) * L_DIM + l0;
            float4 o; o.x = a0; o.y = a1; o.z = a2; o.w = a3;
            *(float4*)dst = o;
        } else {
            ushort4 o; o.x = f2bf(a0); o.y = f2bf(a1);
            o.z = f2bf(a2); o.w = f2bf(a3);
            *(ushort4*)(vbf + (size_t)(b * 64 + d0 + i) * L_DIM + l0) = o;
        }
    }
}

// ---------------------------------------------------------------------------
// Kernel 2: L2-normalize over channels; transpose to [b][l][64] bf16
// (the MFMA A/B operand layout for QK^T: 8 contiguous d per lane).
// grid (64, 2, 2): x = l-tile, y = b, z = 0:Q / 1:K.
// ---------------------------------------------------------------------------
__global__ __launch_bounds__(256) void norm_kernel(
    const float* __restrict__ qraw, const float* __restrict__ kraw,
    unsigned short* __restrict__ qn, unsigned short* __restrict__ kn)
{
    const int which = blockIdx.z, b = blockIdx.y;
    const int l0 = blockIdx.x * 64;
    const float* raw = which ? kraw : qraw;
    unsigned short* outp = which ? kn : qn;

    __shared__ float tile[64][65];   // [d][l], +1 pad
    __shared__ float rn[64];
    const int tid = threadIdx.x;

    for (int idx = tid; idx < 4096; idx += 256) {
        const int d = idx >> 6, l = idx & 63;
        tile[d][l] = raw[(size_t)(b * 64 + d) * L_DIM + l0 + l];
    }
    __syncthreads();
    if (tid < 64) {
        float s = 0.f;
        for (int d = 0; d < 64; ++d) { const float v = tile[d][tid]; s += v * v; }
        rn[tid] = 1.0f / fmaxf(sqrtf(s), 1e-6f);   // x / max(||x||, eps)
    }
    __syncthreads();
    for (int idx = tid; idx < 4096; idx += 256) {
        const int l = idx >> 6, d = idx & 63;      // d fastest -> coalesced store
        outp[((size_t)b * L_DIM + l0 + l) * 64 + d] = f2bf(tile[d][l] * rn[l]);
    }
}

// ---------------------------------------------------------------------------
// Kernel 3: attention with split-j partial softmax (no max rescale needed).
// grid (64, NSPLIT, 2): x = 64-row i-tile, y = j-split, z = b. 4 waves/block,
// wave w owns i-strip [16w,16w+16). No __syncthreads in the j-loop: the P
// transform LDS strip is wave-private.
// MFMA 16x16x32 bf16 layouts (verified, m89/m120):
//   A: lane holds A[m=lane&15][k=(lane>>4)*8+j]   (8 contiguous k)
//   B: lane holds B[k=(lane>>4)*8+j][n=lane&15]
//   C/D: lane holds D[row=(lane>>4)*4+reg][col=lane&15]
// ---------------------------------------------------------------------------
__global__ __launch_bounds__(256) void attn_kernel(
    const unsigned short* __restrict__ qn, const unsigned short* __restrict__ kn,
    const unsigned short* __restrict__ vbf,
    float* __restrict__ opart, float* __restrict__ ssum)
{
    const int b = blockIdx.z, split = blockIdx.y;
    const int i0 = blockIdx.x * 64;
    const int tid = threadIdx.x;
    const int w = tid >> 6, lane = tid & 63, q = lane >> 4, ln = lane & 15;

    const unsigned short* Q = qn + (size_t)b * L_DIM * 64;   // [l][64]
    const unsigned short* K = kn + (size_t)b * L_DIM * 64;   // [l][64]
    const unsigned short* V = vbf + (size_t)b * 64 * L_DIM;  // [v][L]

    __shared__ unsigned short Pl[64][72];   // [i][j] bf16, wave-private 16-row strips

    // Q A-fragments: rows i = i0+16w+ln, k-steps d in [0,32),[32,64). Live all loop.
    bf16x8 qa[2];
    {
        const unsigned short* qp = Q + (size_t)(i0 + w * 16 + ln) * 64 + q * 8;
        qa[0] = *(const bf16x8*)(qp);
        qa[1] = *(const bf16x8*)(qp + 32);
    }

    f32x4 acc[4];   // O strip [16 i][64 v]: 4 C-frags over v
    #pragma unroll
    for (int vf = 0; vf < 4; ++vf) acc[vf] = (f32x4){0.f, 0.f, 0.f, 0.f};
    float rowsum[4] = {0.f, 0.f, 0.f, 0.f};
    const f32x4 zero = (f32x4){0.f, 0.f, 0.f, 0.f};

    const int JT = L_DIM / (NSPLIT * 64);   // 16 j-tiles per split
    for (int jt = 0; jt < JT; ++jt) {
        const int j0 = split * (L_DIM / NSPLIT) + jt * 64;

        // K B-fragments: B[k=d][n=j] = Kn[j][d]
        bf16x8 kf[4][2];
        #pragma unroll
        for (int jf = 0; jf < 4; ++jf) {
            const unsigned short* kp = K + (size_t)(j0 + jf * 16 + ln) * 64 + q * 8;
            kf[jf][0] = *(const bf16x8*)(kp);
            kf[jf][1] = *(const bf16x8*)(kp + 32);
        }

        // S strip = Qn . Kn^T  (16 i x 64 j)
        f32x4 s[4];
        #pragma unroll
        for (int jf = 0; jf < 4; ++jf) {
            s[jf] = __builtin_amdgcn_mfma_f32_16x16x32_bf16(qa[0], kf[jf][0], zero, 0, 0, 0);
            s[jf] = __builtin_amdgcn_mfma_f32_16x16x32_bf16(qa[1], kf[jf][1], s[jf], 0, 0, 0);
        }

        // P = exp(S) (S in [-1,1]: stable); rowsum; pack bf16 into LDS strip
        #pragma unroll
        for (int jf = 0; jf < 4; ++jf) {
            #pragma unroll
            for (int r = 0; r < 4; ++r) {
                const float p = __expf(s[jf][r]);
                rowsum[r] += p;
                Pl[w * 16 + q * 4 + r][jf * 16 + ln] = f2bf(p);
            }
        }

        // P back out in A-operand layout (8 contiguous j per lane)
        bf16x8 pa[2];
        {
            const unsigned short* pp = &Pl[w * 16 + ln][q * 8];
            pa[0] = *(const bf16x8*)(pp);
            pa[1] = *(const bf16x8*)(pp + 32);
        }

        // O += P . V   (V[v][L]: lane reads 8 contiguous j at fixed v = B layout)
        #pragma unroll
        for (int vf = 0; vf < 4; ++vf) {
            const unsigned short* vp = V + (size_t)(vf * 16 + ln) * L_DIM + j0 + q * 8;
            const bf16x8 v0 = *(const bf16x8*)(vp);
            const bf16x8 v1 = *(const bf16x8*)(vp + 32);
            acc[vf] = __builtin_amdgcn_mfma_f32_16x16x32_bf16(pa[0], v0, acc[vf], 0, 0, 0);
            acc[vf] = __builtin_amdgcn_mfma_f32_16x16x32_bf16(pa[1], v1, acc[vf], 0, 0, 0);
        }
    }

    // full row sums: reduce across the 16 lanes (cols) of each quad
    #pragma unroll
    for (int off = 1; off < 16; off <<= 1)
        #pragma unroll
        for (int r = 0; r < 4; ++r) rowsum[r] += __shfl_xor(rowsum[r], off);

    float* Op = opart + ((size_t)(b * NSPLIT + split) * L_DIM + i0) * 64;
    #pragma unroll
    for (int vf = 0; vf < 4; ++vf)
        #pragma unroll
        for (int r = 0; r < 4; ++r)
            Op[(w * 16 + q * 4 + r) * 64 + vf * 16 + ln] = acc[vf][r];

    if (ln == 0) {
        #pragma unroll
        for (int r = 0; r < 4; ++r)
            ssum[(size_t)(b * NSPLIT + split) * L_DIM + i0 + w * 16 + q * 4 + r] = rowsum[r];
    }
}

// ---------------------------------------------------------------------------
// Kernel 4: sum the NSPLIT partials, divide by rowsum, transpose to out [b][v][l].
// grid (64, 2): x = i-tile, y = b.
// ---------------------------------------------------------------------------
__global__ __launch_bounds__(256) void combine_kernel(
    const float* __restrict__ opart, const float* __restrict__ ssum,
    float* __restrict__ out)
{
    const int b = blockIdx.y;
    const int i0 = blockIdx.x * 64;
    const int tid = threadIdx.x;
    __shared__ float t[64][65];
    __shared__ float sinv[64];

    if (tid < 64) {
        float s = 0.f;
        for (int sp = 0; sp < NSPLIT; ++sp)
            s += ssum[(size_t)(b * NSPLIT + sp) * L_DIM + i0 + tid];
        sinv[tid] = 1.0f / s;
    }
    __syncthreads();
    for (int idx = tid; idx < 4096; idx += 256) {
        const int i = idx >> 6, v = idx & 63;   // v fastest -> coalesced reads
        float a = 0.f;
        for (int sp = 0; sp < NSPLIT; ++sp)
            a += opart[((size_t)(b * NSPLIT + sp) * L_DIM + i0 + i) * 64 + v];
        t[i][v] = a;
    }
    __syncthreads();
    for (int idx = tid; idx < 4096; idx += 256) {
        const int v = idx >> 6, i = idx & 63;   // i fastest -> coalesced stores
        out[((size_t)(b * 64 + v)) * L_DIM + i0 + i] = t[i][v] * sinv[i];
    }
}

// ---------------------------------------------------------------------------
extern "C" void kernel_launch(void* const* d_in, const int* in_sizes, int n_in,
                              void* d_out, int out_size, void* d_ws, size_t ws_size,
                              hipStream_t stream)
{
    const float* x  = (const float*)d_in[0];
    const float* xe = (const float*)d_in[1];
    const float* Wq = (const float*)d_in[2];
    const float* bq = (const float*)d_in[3];
    const float* Wk = (const float*)d_in[4];
    const float* bk = (const float*)d_in[5];
    const float* Wv = (const float*)d_in[6];
    const float* bv = (const float*)d_in[7];
    float* out = (float*)d_out;

    char* ws = (char*)d_ws;
    float*          qraw = (float*)(ws);                          // 2 MB
    float*          kraw = (float*)(ws + (2u << 20));             // 2 MB
    unsigned short* qn   = (unsigned short*)(ws + (4u << 20));    // 1 MB
    unsigned short* kn   = (unsigned short*)(ws + (5u << 20));    // 1 MB
    unsigned short* vbf  = (unsigned short*)(ws + (6u << 20));    // 1 MB
    float*          op   = (float*)(ws + (7u << 20));             // 8 MB
    float*          ss   = (float*)(ws + (15u << 20));            // 128 KB

    proj_kernel<<<dim3(8, 8, 6), 128, 0, stream>>>(x, xe, Wq, bq, Wk, bk, Wv, bv,
                                                   qraw, kraw, vbf);
    norm_kernel<<<dim3(64, 2, 2), 256, 0, stream>>>(qraw, kraw, qn, kn);
    attn_kernel<<<dim3(64, NSPLIT, 2), 256, 0, stream>>>(qn, kn, vbf, op, ss);
    combine_kernel<<<dim3(64, 2), 256, 0, stream>>>(op, ss, out);
}

// Round 3
// 162.005 us; speedup vs baseline: 1.5173x; 1.3144x over previous
//
#include <hip/hip_runtime.h>

// SAHead: B=2, Cenc=326, C=320, dk=dv=64, L=64*64=4096.
// Cosine attention => scores in [-1,1] => exp() stable without max-subtraction
// => split-j partial softmax combines by plain addition.
//
// Pipeline: wconv (W fp32->bf16, zero-pad K to 384)
//           xpose (x/xe [c][l] fp32 -> Xt [l][384] bf16, zero-padded)
//           proj  (MFMA GEMM, norm fused in epilogue -> qn/kn [l][64], V [v][L])
//           attn  (flash-style, split-j partial softmax)
//           combine

#define L_DIM 4096
#define KPAD 384
#define NSPLIT 4

typedef __attribute__((ext_vector_type(8))) short bf16x8;  // 8 bf16 (4 VGPRs)
typedef __attribute__((ext_vector_type(4))) float f32x4;   // 4 fp32 acc

__device__ __forceinline__ unsigned short f2bf(float f) {
    // round-to-nearest-even fp32 -> bf16
    unsigned u = __float_as_uint(f);
    u += 0x7fffu + ((u >> 16) & 1u);
    return (unsigned short)(u >> 16);
}

// ---------------------------------------------------------------------------
// Kernel 0: weights fp32 -> bf16, rows padded to KPAD with zeros.
// wbf layout [t][64][KPAD], t = 0:Wq 1:Wk 2:Wv.
// ---------------------------------------------------------------------------
__global__ __launch_bounds__(256) void wconv_kernel(
    const float* __restrict__ Wq, const float* __restrict__ Wk,
    const float* __restrict__ Wv, unsigned short* __restrict__ wbf)
{
    const int idx = blockIdx.x * 256 + threadIdx.x;
    if (idx >= 3 * 64 * KPAD) return;
    const int t = idx / (64 * KPAD);
    const int rem = idx - t * 64 * KPAD;
    const int d = rem / KPAD, c = rem - d * KPAD;
    const int Cin = (t == 2) ? 320 : 326;
    const float* W = (t == 0) ? Wq : (t == 1 ? Wk : Wv);
    wbf[idx] = (c < Cin) ? f2bf(W[(size_t)d * Cin + c]) : (unsigned short)0;
}

// ---------------------------------------------------------------------------
// Kernel 1: transpose+convert x / xe to Xt[b][l][KPAD] bf16 (zero-padded c).
// grid (64 l-tiles, 6 c-tiles, 4): z = src*2 + b (src 0 = xe, 1 = x).
// Coalesced fp32 reads -> LDS [c][l] (+1 pad) -> coalesced ushort4 writes.
// ---------------------------------------------------------------------------
__global__ __launch_bounds__(256) void xpose_kernel(
    const float* __restrict__ x, const float* __restrict__ xe,
    unsigned short* __restrict__ xt_x, unsigned short* __restrict__ xt_xe)
{
    const int z = blockIdx.z;
    const int src_is_x = z >> 1, b = z & 1;
    const int c0 = blockIdx.y * 64;
    const int l0 = blockIdx.x * 64;
    const int Cin = src_is_x ? 320 : 326;
    const float* src = (src_is_x ? x : xe) + (size_t)b * Cin * L_DIM;
    unsigned short* dst = (src_is_x ? xt_x : xt_xe) + (size_t)b * L_DIM * KPAD;

    __shared__ float tile[64][65];
    const int tid = threadIdx.x;

    for (int it = 0; it < 16; ++it) {
        const int idx = tid + it * 256;
        const int cc = idx >> 6, ll = idx & 63;
        const int c = c0 + cc;
        tile[cc][ll] = (c < Cin) ? src[(size_t)c * L_DIM + l0 + ll] : 0.f;
    }
    __syncthreads();
    for (int it = 0; it < 4; ++it) {
        const int idx = tid + it * 256;          // 1024 ushort4 stores
        const int ll = idx >> 4, cq = idx & 15;  // cc = cq*4
        ushort4 o;
        o.x = f2bf(tile[cq * 4 + 0][ll]);
        o.y = f2bf(tile[cq * 4 + 1][ll]);
        o.z = f2bf(tile[cq * 4 + 2][ll]);
        o.w = f2bf(tile[cq * 4 + 3][ll]);
        *(ushort4*)(dst + (size_t)(l0 + ll) * KPAD + c0 + cq * 4) = o;
    }
}

// ---------------------------------------------------------------------------
// Kernel 2: MFMA projection with fused L2-normalize (Q,K) / bf16 store (V).
// One wave (64 thr) per block computes a 64d x 64l tile. grid (64 l-tiles, 6);
// y = tensor*2 + b. No LDS, no barriers; register prefetch pipelines loads.
// MFMA 16x16x32 bf16 layouts (verified via attn correctness):
//   A: lane holds A[m=lane&15][k=(lane>>4)*8+j]  (8 contiguous k)
//   B: lane holds B[k=(lane>>4)*8+j][n=lane&15]
//   D: lane holds D[row=(lane>>4)*4+r][col=lane&15]
// Here A=W (m=d,k=c), B=Xt^T (k=c,n=l), D[d][l].
// ---------------------------------------------------------------------------
__global__ __launch_bounds__(64) void proj_kernel(
    const unsigned short* __restrict__ xt_xe, const unsigned short* __restrict__ xt_x,
    const unsigned short* __restrict__ wbf,
    const float* __restrict__ bq, const float* __restrict__ bk,
    const float* __restrict__ bv,
    unsigned short* __restrict__ qn, unsigned short* __restrict__ kn,
    unsigned short* __restrict__ vbf)
{
    const int z = blockIdx.y;
    const int tensor = z >> 1, b = z & 1;
    const int l0 = blockIdx.x * 64;
    const int lane = threadIdx.x;
    const int q = lane >> 4, ln = lane & 15;

    const unsigned short* Xt = (tensor == 2 ? xt_x : xt_xe) + (size_t)b * L_DIM * KPAD;
    const unsigned short* W  = wbf + (size_t)tensor * 64 * KPAD;
    const float* bias = (tensor == 0) ? bq : (tensor == 1 ? bk : bv);
    const int ksteps = (tensor == 2) ? 10 : 11;   // 320 / 326->352 real cols

    f32x4 acc[4][4];   // [mf][nf]: d = mf*16+q*4+r, l = l0+nf*16+ln
    #pragma unroll
    for (int mf = 0; mf < 4; ++mf)
        #pragma unroll
        for (int nf = 0; nf < 4; ++nf) acc[mf][nf] = (f32x4){0.f, 0.f, 0.f, 0.f};

    bf16x8 af[4], bfr[4], afn[4], bfn[4];
    #pragma unroll
    for (int mf = 0; mf < 4; ++mf)
        af[mf] = *(const bf16x8*)(W + (size_t)(mf * 16 + ln) * KPAD + q * 8);
    #pragma unroll
    for (int nf = 0; nf < 4; ++nf)
        bfr[nf] = *(const bf16x8*)(Xt + (size_t)(l0 + nf * 16 + ln) * KPAD + q * 8);

    for (int ks = 0; ks < ksteps; ++ks) {
        if (ks + 1 < ksteps) {
            const int c = (ks + 1) * 32 + q * 8;
            #pragma unroll
            for (int mf = 0; mf < 4; ++mf)
                afn[mf] = *(const bf16x8*)(W + (size_t)(mf * 16 + ln) * KPAD + c);
            #pragma unroll
            for (int nf = 0; nf < 4; ++nf)
                bfn[nf] = *(const bf16x8*)(Xt + (size_t)(l0 + nf * 16 + ln) * KPAD + c);
        }
        #pragma unroll
        for (int mf = 0; mf < 4; ++mf)
            #pragma unroll
            for (int nf = 0; nf < 4; ++nf)
                acc[mf][nf] = __builtin_amdgcn_mfma_f32_16x16x32_bf16(
                    af[mf], bfr[nf], acc[mf][nf], 0, 0, 0);
        #pragma unroll
        for (int mf = 0; mf < 4; ++mf) af[mf] = afn[mf];
        #pragma unroll
        for (int nf = 0; nf < 4; ++nf) bfr[nf] = bfn[nf];
    }

    // bias (indexed by d = row)
    #pragma unroll
    for (int mf = 0; mf < 4; ++mf)
        #pragma unroll
        for (int r = 0; r < 4; ++r) {
            const float bb = bias[mf * 16 + q * 4 + r];
            #pragma unroll
            for (int nf = 0; nf < 4; ++nf) acc[mf][nf][r] += bb;
        }

    if (tensor < 2) {
        // L2-normalize over d (rows) at fixed l (col): in-lane partial over
        // (mf,r), cross-lane over the 4 row-quads (lanes ^16, ^32).
        unsigned short* outp = (tensor ? kn : qn) + (size_t)b * L_DIM * 64;
        #pragma unroll
        for (int nf = 0; nf < 4; ++nf) {
            float s = 0.f;
            #pragma unroll
            for (int mf = 0; mf < 4; ++mf)
                #pragma unroll
                for (int r = 0; r < 4; ++r) s += acc[mf][nf][r] * acc[mf][nf][r];
            s += __shfl_xor(s, 16);
            s += __shfl_xor(s, 32);
            const float rn = 1.0f / fmaxf(sqrtf(s), 1e-6f);
            const size_t lrow = (size_t)(l0 + nf * 16 + ln) * 64;
            #pragma unroll
            for (int mf = 0; mf < 4; ++mf) {
                ushort4 o;
                o.x = f2bf(acc[mf][nf][0] * rn);
                o.y = f2bf(acc[mf][nf][1] * rn);
                o.z = f2bf(acc[mf][nf][2] * rn);
                o.w = f2bf(acc[mf][nf][3] * rn);
                *(ushort4*)(outp + lrow + mf * 16 + q * 4) = o;
            }
        }
    } else {
        // V: store [b][v][L] bf16 (B-operand layout for PV)
        unsigned short* outp = vbf + (size_t)b * 64 * L_DIM;
        #pragma unroll
        for (int mf = 0; mf < 4; ++mf)
            #pragma unroll
            for (int r = 0; r < 4; ++r) {
                const int v = mf * 16 + q * 4 + r;
                #pragma unroll
                for (int nf = 0; nf < 4; ++nf)
                    outp[(size_t)v * L_DIM + l0 + nf * 16 + ln] = f2bf(acc[mf][nf][r]);
            }
    }
}

// ---------------------------------------------------------------------------
// Kernel 3: attention with split-j partial softmax (no max rescale needed).
// grid (64, NSPLIT, 2): x = 64-row i-tile, y = j-split, z = b. 4 waves/block,
// wave w owns i-strip [16w,16w+16). No __syncthreads in the j-loop: the P
// transform LDS strip is wave-private.
// ---------------------------------------------------------------------------
__global__ __launch_bounds__(256) void attn_kernel(
    const unsigned short* __restrict__ qn, const unsigned short* __restrict__ kn,
    const unsigned short* __restrict__ vbf,
    float* __restrict__ opart, float* __restrict__ ssum)
{
    const int b = blockIdx.z, split = blockIdx.y;
    const int i0 = blockIdx.x * 64;
    const int tid = threadIdx.x;
    const int w = tid >> 6, lane = tid & 63, q = lane >> 4, ln = lane & 15;

    const unsigned short* Q = qn + (size_t)b * L_DIM * 64;   // [l][64]
    const unsigned short* K = kn + (size_t)b * L_DIM * 64;   // [l][64]
    const unsigned short* V = vbf + (size_t)b * 64 * L_DIM;  // [v][L]

    __shared__ unsigned short Pl[64][72];   // [i][j] bf16, wave-private strips

    bf16x8 qa[2];
    {
        const unsigned short* qp = Q + (size_t)(i0 + w * 16 + ln) * 64 + q * 8;
        qa[0] = *(const bf16x8*)(qp);
        qa[1] = *(const bf16x8*)(qp + 32);
    }

    f32x4 acc[4];
    #pragma unroll
    for (int vf = 0; vf < 4; ++vf) acc[vf] = (f32x4){0.f, 0.f, 0.f, 0.f};
    float rowsum[4] = {0.f, 0.f, 0.f, 0.f};
    const f32x4 zero = (f32x4){0.f, 0.f, 0.f, 0.f};

    const int JT = L_DIM / (NSPLIT * 64);
    for (int jt = 0; jt < JT; ++jt) {
        const int j0 = split * (L_DIM / NSPLIT) + jt * 64;

        bf16x8 kf[4][2];
        #pragma unroll
        for (int jf = 0; jf < 4; ++jf) {
            const unsigned short* kp = K + (size_t)(j0 + jf * 16 + ln) * 64 + q * 8;
            kf[jf][0] = *(const bf16x8*)(kp);
            kf[jf][1] = *(const bf16x8*)(kp + 32);
        }

        f32x4 s[4];
        #pragma unroll
        for (int jf = 0; jf < 4; ++jf) {
            s[jf] = __builtin_amdgcn_mfma_f32_16x16x32_bf16(qa[0], kf[jf][0], zero, 0, 0, 0);
            s[jf] = __builtin_amdgcn_mfma_f32_16x16x32_bf16(qa[1], kf[jf][1], s[jf], 0, 0, 0);
        }

        #pragma unroll
        for (int jf = 0; jf < 4; ++jf) {
            #pragma unroll
            for (int r = 0; r < 4; ++r) {
                const float p = __expf(s[jf][r]);
                rowsum[r] += p;
                Pl[w * 16 + q * 4 + r][jf * 16 + ln] = f2bf(p);
            }
        }

        bf16x8 pa[2];
        {
            const unsigned short* pp = &Pl[w * 16 + ln][q * 8];
            pa[0] = *(const bf16x8*)(pp);
            pa[1] = *(const bf16x8*)(pp + 32);
        }

        #pragma unroll
        for (int vf = 0; vf < 4; ++vf) {
            const unsigned short* vp = V + (size_t)(vf * 16 + ln) * L_DIM + j0 + q * 8;
            const bf16x8 v0 = *(const bf16x8*)(vp);
            const bf16x8 v1 = *(const bf16x8*)(vp + 32);
            acc[vf] = __builtin_amdgcn_mfma_f32_16x16x32_bf16(pa[0], v0, acc[vf], 0, 0, 0);
            acc[vf] = __builtin_amdgcn_mfma_f32_16x16x32_bf16(pa[1], v1, acc[vf], 0, 0, 0);
        }
    }

    #pragma unroll
    for (int off = 1; off < 16; off <<= 1)
        #pragma unroll
        for (int r = 0; r < 4; ++r) rowsum[r] += __shfl_xor(rowsum[r], off);

    float* Op = opart + ((size_t)(b * NSPLIT + split) * L_DIM + i0) * 64;
    #pragma unroll
    for (int vf = 0; vf < 4; ++vf)
        #pragma unroll
        for (int r = 0; r < 4; ++r)
            Op[(w * 16 + q * 4 + r) * 64 + vf * 16 + ln] = acc[vf][r];

    if (ln == 0) {
        #pragma unroll
        for (int r = 0; r < 4; ++r)
            ssum[(size_t)(b * NSPLIT + split) * L_DIM + i0 + w * 16 + q * 4 + r] = rowsum[r];
    }
}

// ---------------------------------------------------------------------------
// Kernel 4: sum the NSPLIT partials, divide by rowsum, transpose to [b][v][l].
// ---------------------------------------------------------------------------
__global__ __launch_bounds__(256) void combine_kernel(
    const float* __restrict__ opart, const float* __restrict__ ssum,
    float* __restrict__ out)
{
    const int b = blockIdx.y;
    const int i0 = blockIdx.x * 64;
    const int tid = threadIdx.x;
    __shared__ float t[64][65];
    __shared__ float sinv[64];

    if (tid < 64) {
        float s = 0.f;
        for (int sp = 0; sp < NSPLIT; ++sp)
            s += ssum[(size_t)(b * NSPLIT + sp) * L_DIM + i0 + tid];
        sinv[tid] = 1.0f / s;
    }
    __syncthreads();
    for (int idx = tid; idx < 4096; idx += 256) {
        const int i = idx >> 6, v = idx & 63;
        float a = 0.f;
        for (int sp = 0; sp < NSPLIT; ++sp)
            a += opart[((size_t)(b * NSPLIT + sp) * L_DIM + i0 + i) * 64 + v];
        t[i][v] = a;
    }
    __syncthreads();
    for (int idx = tid; idx < 4096; idx += 256) {
        const int v = idx >> 6, i = idx & 63;
        out[((size_t)(b * 64 + v)) * L_DIM + i0 + i] = t[i][v] * sinv[i];
    }
}

// ---------------------------------------------------------------------------
extern "C" void kernel_launch(void* const* d_in, const int* in_sizes, int n_in,
                              void* d_out, int out_size, void* d_ws, size_t ws_size,
                              hipStream_t stream)
{
    const float* x  = (const float*)d_in[0];
    const float* xe = (const float*)d_in[1];
    const float* Wq = (const float*)d_in[2];
    const float* bq = (const float*)d_in[3];
    const float* Wk = (const float*)d_in[4];
    const float* bk = (const float*)d_in[5];
    const float* Wv = (const float*)d_in[6];
    const float* bv = (const float*)d_in[7];
    float* out = (float*)d_out;

    char* ws = (char*)d_ws;
    unsigned short* qn   = (unsigned short*)(ws);                  // 1 MB
    unsigned short* kn   = (unsigned short*)(ws + (1u << 20));     // 1 MB
    unsigned short* vbf  = (unsigned short*)(ws + (2u << 20));     // 1 MB
    float*          op   = (float*)(ws + (3u << 20));              // 8 MB
    float*          ss   = (float*)(ws + (11u << 20));             // 128 KB
    unsigned short* xtxe = (unsigned short*)(ws + (12u << 20));    // 6 MB
    unsigned short* xtx  = (unsigned short*)(ws + (18u << 20));    // 6 MB
    unsigned short* wb   = (unsigned short*)(ws + (24u << 20));    // 144 KB

    wconv_kernel<<<dim3((3 * 64 * KPAD + 255) / 256), 256, 0, stream>>>(Wq, Wk, Wv, wb);
    xpose_kernel<<<dim3(64, 6, 4), 256, 0, stream>>>(x, xe, xtx, xtxe);
    proj_kernel<<<dim3(64, 6), 64, 0, stream>>>(xtxe, xtx, wb, bq, bk, bv, qn, kn, vbf);
    attn_kernel<<<dim3(64, NSPLIT, 2), 256, 0, stream>>>(qn, kn, vbf, op, ss);
    combine_kernel<<<dim3(64, 2), 256, 0, stream>>>(op, ss, out);
}

// Round 4
// 131.497 us; speedup vs baseline: 1.8693x; 1.2320x over previous
//
#include <hip/hip_runtime.h>

// SAHead: B=2, Cenc=326, C=320, dk=dv=64, L=64*64=4096.
// Cosine attention => scores in [-1,1] => exp() stable without max-subtraction
// => split-j partial softmax combines by plain addition.
//
// Pipeline: wconv (W fp32->bf16, zero-pad K to 384)
//           xpose (x/xe [c][l] fp32 -> Xt [l][384] bf16, zero-padded)
//           proj  (MFMA GEMM, norm fused in epilogue -> qn/kn [l][64], V [v][L])
//           attn  (flash-style, split-j partial softmax, LDS-staged K/V)
//           combine

#define L_DIM 4096
#define KPAD 384
#define NSPLIT 8

typedef __attribute__((ext_vector_type(8))) short bf16x8;  // 8 bf16 (4 VGPRs)
typedef __attribute__((ext_vector_type(4))) float f32x4;   // 4 fp32 acc

__device__ __forceinline__ unsigned short f2bf(float f) {
    // round-to-nearest-even fp32 -> bf16
    unsigned u = __float_as_uint(f);
    u += 0x7fffu + ((u >> 16) & 1u);
    return (unsigned short)(u >> 16);
}

// ---------------------------------------------------------------------------
// Kernel 0: weights fp32 -> bf16, rows padded to KPAD with zeros.
// ---------------------------------------------------------------------------
__global__ __launch_bounds__(256) void wconv_kernel(
    const float* __restrict__ Wq, const float* __restrict__ Wk,
    const float* __restrict__ Wv, unsigned short* __restrict__ wbf)
{
    const int idx = blockIdx.x * 256 + threadIdx.x;
    if (idx >= 3 * 64 * KPAD) return;
    const int t = idx / (64 * KPAD);
    const int rem = idx - t * 64 * KPAD;
    const int d = rem / KPAD, c = rem - d * KPAD;
    const int Cin = (t == 2) ? 320 : 326;
    const float* W = (t == 0) ? Wq : (t == 1 ? Wk : Wv);
    wbf[idx] = (c < Cin) ? f2bf(W[(size_t)d * Cin + c]) : (unsigned short)0;
}

// ---------------------------------------------------------------------------
// Kernel 1: transpose+convert x / xe to Xt[b][l][KPAD] bf16 (zero-padded c).
// ---------------------------------------------------------------------------
__global__ __launch_bounds__(256) void xpose_kernel(
    const float* __restrict__ x, const float* __restrict__ xe,
    unsigned short* __restrict__ xt_x, unsigned short* __restrict__ xt_xe)
{
    const int z = blockIdx.z;
    const int src_is_x = z >> 1, b = z & 1;
    const int c0 = blockIdx.y * 64;
    const int l0 = blockIdx.x * 64;
    const int Cin = src_is_x ? 320 : 326;
    const float* src = (src_is_x ? x : xe) + (size_t)b * Cin * L_DIM;
    unsigned short* dst = (src_is_x ? xt_x : xt_xe) + (size_t)b * L_DIM * KPAD;

    __shared__ float tile[64][65];
    const int tid = threadIdx.x;

    for (int it = 0; it < 16; ++it) {
        const int idx = tid + it * 256;
        const int cc = idx >> 6, ll = idx & 63;
        const int c = c0 + cc;
        tile[cc][ll] = (c < Cin) ? src[(size_t)c * L_DIM + l0 + ll] : 0.f;
    }
    __syncthreads();
    for (int it = 0; it < 4; ++it) {
        const int idx = tid + it * 256;
        const int ll = idx >> 4, cq = idx & 15;
        ushort4 o;
        o.x = f2bf(tile[cq * 4 + 0][ll]);
        o.y = f2bf(tile[cq * 4 + 1][ll]);
        o.z = f2bf(tile[cq * 4 + 2][ll]);
        o.w = f2bf(tile[cq * 4 + 3][ll]);
        *(ushort4*)(dst + (size_t)(l0 + ll) * KPAD + c0 + cq * 4) = o;
    }
}

// ---------------------------------------------------------------------------
// Kernel 2: MFMA projection with fused L2-normalize (Q,K) / bf16 store (V).
// One wave per block computes a 64d x 64l tile. grid (64 l-tiles, 6).
// ---------------------------------------------------------------------------
__global__ __launch_bounds__(64) void proj_kernel(
    const unsigned short* __restrict__ xt_xe, const unsigned short* __restrict__ xt_x,
    const unsigned short* __restrict__ wbf,
    const float* __restrict__ bq, const float* __restrict__ bk,
    const float* __restrict__ bv,
    unsigned short* __restrict__ qn, unsigned short* __restrict__ kn,
    unsigned short* __restrict__ vbf)
{
    const int z = blockIdx.y;
    const int tensor = z >> 1, b = z & 1;
    const int l0 = blockIdx.x * 64;
    const int lane = threadIdx.x;
    const int q = lane >> 4, ln = lane & 15;

    const unsigned short* Xt = (tensor == 2 ? xt_x : xt_xe) + (size_t)b * L_DIM * KPAD;
    const unsigned short* W  = wbf + (size_t)tensor * 64 * KPAD;
    const float* bias = (tensor == 0) ? bq : (tensor == 1 ? bk : bv);
    const int ksteps = (tensor == 2) ? 10 : 11;

    f32x4 acc[4][4];
    #pragma unroll
    for (int mf = 0; mf < 4; ++mf)
        #pragma unroll
        for (int nf = 0; nf < 4; ++nf) acc[mf][nf] = (f32x4){0.f, 0.f, 0.f, 0.f};

    bf16x8 af[4], bfr[4], afn[4], bfn[4];
    #pragma unroll
    for (int mf = 0; mf < 4; ++mf)
        af[mf] = *(const bf16x8*)(W + (size_t)(mf * 16 + ln) * KPAD + q * 8);
    #pragma unroll
    for (int nf = 0; nf < 4; ++nf)
        bfr[nf] = *(const bf16x8*)(Xt + (size_t)(l0 + nf * 16 + ln) * KPAD + q * 8);

    for (int ks = 0; ks < ksteps; ++ks) {
        if (ks + 1 < ksteps) {
            const int c = (ks + 1) * 32 + q * 8;
            #pragma unroll
            for (int mf = 0; mf < 4; ++mf)
                afn[mf] = *(const bf16x8*)(W + (size_t)(mf * 16 + ln) * KPAD + c);
            #pragma unroll
            for (int nf = 0; nf < 4; ++nf)
                bfn[nf] = *(const bf16x8*)(Xt + (size_t)(l0 + nf * 16 + ln) * KPAD + c);
        }
        #pragma unroll
        for (int mf = 0; mf < 4; ++mf)
            #pragma unroll
            for (int nf = 0; nf < 4; ++nf)
                acc[mf][nf] = __builtin_amdgcn_mfma_f32_16x16x32_bf16(
                    af[mf], bfr[nf], acc[mf][nf], 0, 0, 0);
        #pragma unroll
        for (int mf = 0; mf < 4; ++mf) af[mf] = afn[mf];
        #pragma unroll
        for (int nf = 0; nf < 4; ++nf) bfr[nf] = bfn[nf];
    }

    #pragma unroll
    for (int mf = 0; mf < 4; ++mf)
        #pragma unroll
        for (int r = 0; r < 4; ++r) {
            const float bb = bias[mf * 16 + q * 4 + r];
            #pragma unroll
            for (int nf = 0; nf < 4; ++nf) acc[mf][nf][r] += bb;
        }

    if (tensor < 2) {
        unsigned short* outp = (tensor ? kn : qn) + (size_t)b * L_DIM * 64;
        #pragma unroll
        for (int nf = 0; nf < 4; ++nf) {
            float s = 0.f;
            #pragma unroll
            for (int mf = 0; mf < 4; ++mf)
                #pragma unroll
                for (int r = 0; r < 4; ++r) s += acc[mf][nf][r] * acc[mf][nf][r];
            s += __shfl_xor(s, 16);
            s += __shfl_xor(s, 32);
            const float rn = 1.0f / fmaxf(sqrtf(s), 1e-6f);
            const size_t lrow = (size_t)(l0 + nf * 16 + ln) * 64;
            #pragma unroll
            for (int mf = 0; mf < 4; ++mf) {
                ushort4 o;
                o.x = f2bf(acc[mf][nf][0] * rn);
                o.y = f2bf(acc[mf][nf][1] * rn);
                o.z = f2bf(acc[mf][nf][2] * rn);
                o.w = f2bf(acc[mf][nf][3] * rn);
                *(ushort4*)(outp + lrow + mf * 16 + q * 4) = o;
            }
        }
    } else {
        unsigned short* outp = vbf + (size_t)b * 64 * L_DIM;
        #pragma unroll
        for (int mf = 0; mf < 4; ++mf)
            #pragma unroll
            for (int r = 0; r < 4; ++r) {
                const int v = mf * 16 + q * 4 + r;
                #pragma unroll
                for (int nf = 0; nf < 4; ++nf)
                    outp[(size_t)v * L_DIM + l0 + nf * 16 + ln] = f2bf(acc[mf][nf][r]);
            }
    }
}

// ---------------------------------------------------------------------------
// Kernel 3: attention, LDS-staged K/V shared by 4 waves, software-pipelined.
// grid (32, NSPLIT, 2): x = 128-row i-tile, y = j-split, z = b.
// Wave w owns i-strip [32w, 32w+32) as two 16-row substrips. Per 64-j tile:
// stage K(8KB)+V(8KB) in LDS (padded rows, 2-way-free banks); 32 MFMA/wave.
// Next tile's global loads are issued before compute and written after the
// barrier (m97-style pipelining).
// ---------------------------------------------------------------------------
__global__ __launch_bounds__(256) void attn_kernel(
    const unsigned short* __restrict__ qn, const unsigned short* __restrict__ kn,
    const unsigned short* __restrict__ vbf,
    float* __restrict__ opart, float* __restrict__ ssum)
{
    const int b = blockIdx.z, split = blockIdx.y;
    const int i0 = blockIdx.x * 128;
    const int tid = threadIdx.x;
    const int w = tid >> 6, lane = tid & 63, q = lane >> 4, ln = lane & 15;

    const unsigned short* Q = qn + (size_t)b * L_DIM * 64;   // [l][64]
    const unsigned short* K = kn + (size_t)b * L_DIM * 64;   // [l][64]
    const unsigned short* V = vbf + (size_t)b * 64 * L_DIM;  // [v][L]

    __shared__ unsigned short Kb[64][72];     // [j][d], +8 pad (2-way banks)
    __shared__ unsigned short Vb[64][72];     // [v][j], +8 pad
    __shared__ unsigned short Pl[4][32][72];  // wave-private P strips

    // Q A-frags for the wave's two 16-row substrips (live whole loop)
    bf16x8 qa[2][2];
    #pragma unroll
    for (int s = 0; s < 2; ++s) {
        const unsigned short* qp = Q + (size_t)(i0 + w * 32 + s * 16 + ln) * 64 + q * 8;
        qa[s][0] = *(const bf16x8*)(qp);
        qa[s][1] = *(const bf16x8*)(qp + 32);
    }

    f32x4 acc[2][4];
    #pragma unroll
    for (int s = 0; s < 2; ++s)
        #pragma unroll
        for (int vf = 0; vf < 4; ++vf) acc[s][vf] = (f32x4){0.f, 0.f, 0.f, 0.f};
    float rowsum[2][4] = {{0.f,0.f,0.f,0.f},{0.f,0.f,0.f,0.f}};
    const f32x4 zero = (f32x4){0.f, 0.f, 0.f, 0.f};

    const int jbase = split * (L_DIM / NSPLIT);
    const int JT = L_DIM / (NSPLIT * 64);   // 8 j-tiles per split

    bf16x8 kst[2], vst[2];
    // prologue: stage tile 0
    #pragma unroll
    for (int p = 0; p < 2; ++p) {
        const int idx = p * 256 + tid;
        kst[p] = *(const bf16x8*)(K + (size_t)jbase * 64 + idx * 8);
        vst[p] = *(const bf16x8*)(V + (size_t)(idx >> 3) * L_DIM + jbase + (idx & 7) * 8);
    }
    #pragma unroll
    for (int p = 0; p < 2; ++p) {
        const int idx = p * 256 + tid;
        *(bf16x8*)&Kb[idx >> 3][(idx & 7) * 8] = kst[p];
        *(bf16x8*)&Vb[idx >> 3][(idx & 7) * 8] = vst[p];
    }
    __syncthreads();

    for (int jt = 0; jt < JT; ++jt) {
        // issue next tile's global loads (in flight across the compute phase)
        if (jt + 1 < JT) {
            const int j0 = jbase + (jt + 1) * 64;
            #pragma unroll
            for (int p = 0; p < 2; ++p) {
                const int idx = p * 256 + tid;
                kst[p] = *(const bf16x8*)(K + (size_t)j0 * 64 + idx * 8);
                vst[p] = *(const bf16x8*)(V + (size_t)(idx >> 3) * L_DIM + j0 + (idx & 7) * 8);
            }
        }

        // K B-frags from LDS (shared by both substrips)
        bf16x8 kf[4][2];
        #pragma unroll
        for (int jf = 0; jf < 4; ++jf) {
            kf[jf][0] = *(const bf16x8*)&Kb[jf * 16 + ln][q * 8];
            kf[jf][1] = *(const bf16x8*)&Kb[jf * 16 + ln][q * 8 + 32];
        }

        // S = Qn.Kn^T, P = exp(S), pack into wave-private LDS strip
        #pragma unroll
        for (int s = 0; s < 2; ++s) {
            f32x4 sv[4];
            #pragma unroll
            for (int jf = 0; jf < 4; ++jf) {
                sv[jf] = __builtin_amdgcn_mfma_f32_16x16x32_bf16(qa[s][0], kf[jf][0], zero, 0, 0, 0);
                sv[jf] = __builtin_amdgcn_mfma_f32_16x16x32_bf16(qa[s][1], kf[jf][1], sv[jf], 0, 0, 0);
            }
            #pragma unroll
            for (int jf = 0; jf < 4; ++jf)
                #pragma unroll
                for (int r = 0; r < 4; ++r) {
                    const float p = __expf(sv[jf][r]);
                    rowsum[s][r] += p;
                    Pl[w][s * 16 + q * 4 + r][jf * 16 + ln] = f2bf(p);
                }
        }

        // V B-frags from LDS (shared by both substrips)
        bf16x8 vfr[4][2];
        #pragma unroll
        for (int vf = 0; vf < 4; ++vf) {
            vfr[vf][0] = *(const bf16x8*)&Vb[vf * 16 + ln][q * 8];
            vfr[vf][1] = *(const bf16x8*)&Vb[vf * 16 + ln][q * 8 + 32];
        }

        // O += P.V
        #pragma unroll
        for (int s = 0; s < 2; ++s) {
            const bf16x8 pa0 = *(const bf16x8*)&Pl[w][s * 16 + ln][q * 8];
            const bf16x8 pa1 = *(const bf16x8*)&Pl[w][s * 16 + ln][q * 8 + 32];
            #pragma unroll
            for (int vf = 0; vf < 4; ++vf) {
                acc[s][vf] = __builtin_amdgcn_mfma_f32_16x16x32_bf16(pa0, vfr[vf][0], acc[s][vf], 0, 0, 0);
                acc[s][vf] = __builtin_amdgcn_mfma_f32_16x16x32_bf16(pa1, vfr[vf][1], acc[s][vf], 0, 0, 0);
            }
        }

        __syncthreads();   // all waves done reading Kb/Vb
        if (jt + 1 < JT) {
            #pragma unroll
            for (int p = 0; p < 2; ++p) {
                const int idx = p * 256 + tid;
                *(bf16x8*)&Kb[idx >> 3][(idx & 7) * 8] = kst[p];
                *(bf16x8*)&Vb[idx >> 3][(idx & 7) * 8] = vst[p];
            }
            __syncthreads();
        }
    }

    #pragma unroll
    for (int off = 1; off < 16; off <<= 1)
        #pragma unroll
        for (int s = 0; s < 2; ++s)
            #pragma unroll
            for (int r = 0; r < 4; ++r)
                rowsum[s][r] += __shfl_xor(rowsum[s][r], off);

    float* Op = opart + ((size_t)(b * NSPLIT + split) * L_DIM + i0 + w * 32) * 64;
    #pragma unroll
    for (int s = 0; s < 2; ++s)
        #pragma unroll
        for (int vf = 0; vf < 4; ++vf)
            #pragma unroll
            for (int r = 0; r < 4; ++r)
                Op[(s * 16 + q * 4 + r) * 64 + vf * 16 + ln] = acc[s][vf][r];

    if (ln == 0) {
        #pragma unroll
        for (int s = 0; s < 2; ++s)
            #pragma unroll
            for (int r = 0; r < 4; ++r)
                ssum[(size_t)(b * NSPLIT + split) * L_DIM + i0 + w * 32 + s * 16 + q * 4 + r]
                    = rowsum[s][r];
    }
}

// ---------------------------------------------------------------------------
// Kernel 4: sum the NSPLIT partials, divide by rowsum, transpose to [b][v][l].
// ---------------------------------------------------------------------------
__global__ __launch_bounds__(256) void combine_kernel(
    const float* __restrict__ opart, const float* __restrict__ ssum,
    float* __restrict__ out)
{
    const int b = blockIdx.y;
    const int i0 = blockIdx.x * 64;
    const int tid = threadIdx.x;
    __shared__ float t[64][65];
    __shared__ float sinv[64];

    if (tid < 64) {
        float s = 0.f;
        for (int sp = 0; sp < NSPLIT; ++sp)
            s += ssum[(size_t)(b * NSPLIT + sp) * L_DIM + i0 + tid];
        sinv[tid] = 1.0f / s;
    }
    __syncthreads();
    for (int idx = tid; idx < 4096; idx += 256) {
        const int i = idx >> 6, v = idx & 63;
        float a = 0.f;
        for (int sp = 0; sp < NSPLIT; ++sp)
            a += opart[((size_t)(b * NSPLIT + sp) * L_DIM + i0 + i) * 64 + v];
        t[i][v] = a;
    }
    __syncthreads();
    for (int idx = tid; idx < 4096; idx += 256) {
        const int v = idx >> 6, i = idx & 63;
        out[((size_t)(b * 64 + v)) * L_DIM + i0 + i] = t[i][v] * sinv[i];
    }
}

// ---------------------------------------------------------------------------
extern "C" void kernel_launch(void* const* d_in, const int* in_sizes, int n_in,
                              void* d_out, int out_size, void* d_ws, size_t ws_size,
                              hipStream_t stream)
{
    const float* x  = (const float*)d_in[0];
    const float* xe = (const float*)d_in[1];
    const float* Wq = (const float*)d_in[2];
    const float* bq = (const float*)d_in[3];
    const float* Wk = (const float*)d_in[4];
    const float* bk = (const float*)d_in[5];
    const float* Wv = (const float*)d_in[6];
    const float* bv = (const float*)d_in[7];
    float* out = (float*)d_out;

    // ws layout (24 MB total): op (16 MB) overlaps xt buffers (dead after proj;
    // attn writes op strictly after proj in stream order).
    char* ws = (char*)d_ws;
    unsigned short* qn   = (unsigned short*)(ws);                    // 0..1 MB
    unsigned short* kn   = (unsigned short*)(ws + (1u << 20));       // 1..2 MB
    unsigned short* vbf  = (unsigned short*)(ws + (2u << 20));       // 2..3 MB
    float*          ss   = (float*)(ws + (3u << 20));                // 3..3.25 MB
    unsigned short* wb   = (unsigned short*)(ws + (3u << 20) + (512u << 10)); // 3.5..3.65 MB
    unsigned short* xtxe = (unsigned short*)(ws + (4u << 20));       // 4..10 MB
    unsigned short* xtx  = (unsigned short*)(ws + (10u << 20));      // 10..16 MB
    float*          op   = (float*)(ws + (8u << 20));                // 8..24 MB (overlaps xt)

    wconv_kernel<<<dim3((3 * 64 * KPAD + 255) / 256), 256, 0, stream>>>(Wq, Wk, Wv, wb);
    xpose_kernel<<<dim3(64, 6, 4), 256, 0, stream>>>(x, xe, xtx, xtxe);
    proj_kernel<<<dim3(64, 6), 64, 0, stream>>>(xtxe, xtx, wb, bq, bk, bv, qn, kn, vbf);
    attn_kernel<<<dim3(32, NSPLIT, 2), 256, 0, stream>>>(qn, kn, vbf, op, ss);
    combine_kernel<<<dim3(64, 2), 256, 0, stream>>>(op, ss, out);
}